// Round 1
// baseline (711.110 us; speedup 1.0000x reference)
//
#include <hip/hip_runtime.h>
#include <math.h>

// Problem constants (fixed by the reference file).
#define D_FEAT   128
#define NUM_SEG  16384

__device__ __forceinline__ float4 f4max(float4 a, float4 b) {
    return make_float4(fmaxf(a.x, b.x), fmaxf(a.y, b.y), fmaxf(a.z, b.z), fmaxf(a.w, b.w));
}
__device__ __forceinline__ float4 f4min(float4 a, float4 b) {
    return make_float4(fminf(a.x, b.x), fminf(a.y, b.y), fminf(a.z, b.z), fminf(a.w, b.w));
}
__device__ __forceinline__ float4 f4add(float4 a, float4 b) {
    return make_float4(a.x + b.x, a.y + b.y, a.z + b.z, a.w + b.w);
}

// One block (128 threads = 2 waves) per segment. segment_ids is sorted, so a
// segment is a contiguous row range found by binary search. Threads are
// (row_offset = t>>5, col4 = t&31): each loop iteration the block reads 4 full
// rows as float4 (1 KiB contiguous per wave). Per-lane accumulators hold
// max/min/sum/sumsq for 4 feature columns; a small LDS transpose combines the
// 4 row-offset partials, then 32 lanes compute mean/std and store 2 KiB
// contiguous output per segment.
__global__ __launch_bounds__(128) void seg_pool_kernel(
    const float* __restrict__ x,
    const int*   __restrict__ seg32,   // may actually be int64 data; detected below
    float*       __restrict__ out,
    int n)
{
    const int g = blockIdx.x;
    const int t = threadIdx.x;

    __shared__ int sb[2];
    if (t < 2) {
        // Runtime dtype detection: ids are sorted, 0 <= id < 16384, and the
        // last id is ~16383 almost surely. If the int32 view's element [n-1]
        // is 0, it is the high word of an int64 array -> 64-bit ids.
        const bool wide = (seg32[n - 1] == 0);
        const int target = g + t;
        int lo = 0, hi = n;
        if (wide) {
            const long long* s = (const long long*)seg32;
            const long long tgt = (long long)target;
            while (lo < hi) { int m = (lo + hi) >> 1; if (s[m] < tgt) lo = m + 1; else hi = m; }
        } else {
            while (lo < hi) { int m = (lo + hi) >> 1; if (seg32[m] < target) lo = m + 1; else hi = m; }
        }
        sb[t] = lo;
    }
    __syncthreads();
    const int start = sb[0];
    const int end   = sb[1];
    const int cnt   = end - start;

    const int ro = t >> 5;   // 0..3: which row within a 4-row step
    const int c4 = t & 31;   // 0..31: which float4 column

    float4 mx = make_float4(-INFINITY, -INFINITY, -INFINITY, -INFINITY);
    float4 mn = make_float4( INFINITY,  INFINITY,  INFINITY,  INFINITY);
    float4 sm = make_float4(0.f, 0.f, 0.f, 0.f);
    float4 sq = make_float4(0.f, 0.f, 0.f, 0.f);

    for (int r = start + ro; r < end; r += 4) {
        const float4 v = *(const float4*)(x + (size_t)r * D_FEAT + (c4 << 2));
        mx = f4max(mx, v);
        mn = f4min(mn, v);
        sm = f4add(sm, v);
        sq.x = fmaf(v.x, v.x, sq.x);
        sq.y = fmaf(v.y, v.y, sq.y);
        sq.z = fmaf(v.z, v.z, sq.z);
        sq.w = fmaf(v.w, v.w, sq.w);
    }

    // Combine the 4 row-offset partials through LDS: red[stat][ro][c4].
    __shared__ float4 red[4][4][32];   // 8 KiB
    red[0][ro][c4] = mx;
    red[1][ro][c4] = mn;
    red[2][ro][c4] = sm;
    red[3][ro][c4] = sq;
    __syncthreads();

    if (t < 32) {
        float4 MX = red[0][0][t];
        float4 MN = red[1][0][t];
        float4 SM = red[2][0][t];
        float4 SQ = red[3][0][t];
        #pragma unroll
        for (int r = 1; r < 4; ++r) {
            MX = f4max(MX, red[0][r][t]);
            MN = f4min(MN, red[1][r][t]);
            SM = f4add(SM, red[2][r][t]);
            SQ = f4add(SQ, red[3][r][t]);
        }

        const float fc    = (float)cnt;
        const float inv_c = 1.0f / fc;
        const float inv_m = 1.0f / (fc - 1.0f);

        float4 MEAN = make_float4(SM.x * inv_c, SM.y * inv_c, SM.z * inv_c, SM.w * inv_c);
        // Unbiased variance, same formula as the reference:
        // var = (sumsq - cnt*mean^2) / (cnt - 1), clamped at 0.
        float4 STD;
        STD.x = sqrtf(fmaxf((SQ.x - fc * MEAN.x * MEAN.x) * inv_m, 0.0f));
        STD.y = sqrtf(fmaxf((SQ.y - fc * MEAN.y * MEAN.y) * inv_m, 0.0f));
        STD.z = sqrtf(fmaxf((SQ.z - fc * MEAN.z * MEAN.z) * inv_m, 0.0f));
        STD.w = sqrtf(fmaxf((SQ.w - fc * MEAN.w * MEAN.w) * inv_m, 0.0f));

        float* base = out + (size_t)g * 4 * D_FEAT + (t << 2);
        *(float4*)(base + 0 * D_FEAT) = MX;
        *(float4*)(base + 1 * D_FEAT) = MN;
        *(float4*)(base + 2 * D_FEAT) = MEAN;
        *(float4*)(base + 3 * D_FEAT) = STD;
    }
}

extern "C" void kernel_launch(void* const* d_in, const int* in_sizes, int n_in,
                              void* d_out, int out_size, void* d_ws, size_t ws_size,
                              hipStream_t stream) {
    const float* x   = (const float*)d_in[0];
    const int*   seg = (const int*)d_in[1];
    float*       out = (float*)d_out;
    const int n = in_sizes[0] / D_FEAT;   // 1048576 rows

    seg_pool_kernel<<<NUM_SEG, 128, 0, stream>>>(x, seg, out, n);
}

// Round 2
// 698.212 us; speedup vs baseline: 1.0185x; 1.0185x over previous
//
#include <hip/hip_runtime.h>
#include <math.h>

// Problem constants (fixed by the reference file).
#define D_FEAT   128
#define NUM_SEG  16384

__device__ __forceinline__ float4 f4max(float4 a, float4 b) {
    return make_float4(fmaxf(a.x, b.x), fmaxf(a.y, b.y), fmaxf(a.z, b.z), fmaxf(a.w, b.w));
}
__device__ __forceinline__ float4 f4min(float4 a, float4 b) {
    return make_float4(fminf(a.x, b.x), fminf(a.y, b.y), fminf(a.z, b.z), fminf(a.w, b.w));
}
__device__ __forceinline__ float4 f4add(float4 a, float4 b) {
    return make_float4(a.x + b.x, a.y + b.y, a.z + b.z, a.w + b.w);
}

// Phase 1: one pass over sorted segment_ids -> offs[g] = first row with id >= g,
// offs[NUM_SEG] = n. Replaces 16384 x 2 binary searches (each ~20 dependent
// scattered loads) with one coalesced stream over the 4/8 MiB id array.
__global__ __launch_bounds__(256) void seg_bounds_kernel(
    const int* __restrict__ seg32, int* __restrict__ offs, int n)
{
    const int i = blockIdx.x * 256 + threadIdx.x;
    if (i >= n) return;
    // Runtime dtype detection (ids sorted, 0 <= id < 16384): if the int32
    // view's last element is 0 it's the high word of an int64 array.
    const bool wide = (seg32[n - 1] == 0);
    int cur, prev;
    if (wide) {
        const long long* s = (const long long*)seg32;
        cur  = (int)s[i];
        prev = (i == 0) ? -1 : (int)s[i - 1];
    } else {
        cur  = seg32[i];
        prev = (i == 0) ? -1 : seg32[i - 1];
    }
    for (int g = prev + 1; g <= cur; ++g) offs[g] = i;   // writes only at boundaries
    if (i == n - 1) {
        for (int g = cur + 1; g <= NUM_SEG; ++g) offs[g] = n;
    }
}

// Phase 2: one block (128 threads = 2 waves) per segment. Threads are
// (row_offset = t>>5, col4 = t&31). Row loop unrolled x4: each lane keeps 4
// independent global_load_dwordx4 in flight (rows r, r+4, r+8, r+12), so the
// loop is bandwidth-bound instead of serialized on per-load latency.
__global__ __launch_bounds__(128) void seg_pool_kernel(
    const float* __restrict__ x,
    const int*   __restrict__ offs,
    float*       __restrict__ out)
{
    const int g = blockIdx.x;
    const int t = threadIdx.x;

    const int start = offs[g];
    const int end   = offs[g + 1];
    const int cnt   = end - start;

    const int ro = t >> 5;   // 0..3: row offset within a 4-row step
    const int c4 = t & 31;   // 0..31: which float4 column

    float4 mx = make_float4(-INFINITY, -INFINITY, -INFINITY, -INFINITY);
    float4 mn = make_float4( INFINITY,  INFINITY,  INFINITY,  INFINITY);
    float4 sm = make_float4(0.f, 0.f, 0.f, 0.f);
    float4 sq = make_float4(0.f, 0.f, 0.f, 0.f);

    const float* xc = x + (c4 << 2);
    int r = start + ro;

    #define ACC(v) do {                         \
        mx = f4max(mx, (v));                    \
        mn = f4min(mn, (v));                    \
        sm = f4add(sm, (v));                    \
        sq.x = fmaf((v).x, (v).x, sq.x);        \
        sq.y = fmaf((v).y, (v).y, sq.y);        \
        sq.z = fmaf((v).z, (v).z, sq.z);        \
        sq.w = fmaf((v).w, (v).w, sq.w);        \
    } while (0)

    for (; r + 12 < end; r += 16) {
        // 4 independent loads issued before any use -> 4 in flight.
        const float4 v0 = *(const float4*)(xc + (size_t)(r     ) * D_FEAT);
        const float4 v1 = *(const float4*)(xc + (size_t)(r +  4) * D_FEAT);
        const float4 v2 = *(const float4*)(xc + (size_t)(r +  8) * D_FEAT);
        const float4 v3 = *(const float4*)(xc + (size_t)(r + 12) * D_FEAT);
        ACC(v0); ACC(v1); ACC(v2); ACC(v3);
    }
    for (; r < end; r += 4) {
        const float4 v = *(const float4*)(xc + (size_t)r * D_FEAT);
        ACC(v);
    }
    #undef ACC

    // Combine the 4 row-offset partials through LDS: red[stat][ro][c4].
    __shared__ float4 red[4][4][32];   // 8 KiB
    red[0][ro][c4] = mx;
    red[1][ro][c4] = mn;
    red[2][ro][c4] = sm;
    red[3][ro][c4] = sq;
    __syncthreads();

    if (t < 32) {
        float4 MX = red[0][0][t];
        float4 MN = red[1][0][t];
        float4 SM = red[2][0][t];
        float4 SQ = red[3][0][t];
        #pragma unroll
        for (int rr = 1; rr < 4; ++rr) {
            MX = f4max(MX, red[0][rr][t]);
            MN = f4min(MN, red[1][rr][t]);
            SM = f4add(SM, red[2][rr][t]);
            SQ = f4add(SQ, red[3][rr][t]);
        }

        const float fc    = (float)cnt;
        const float inv_c = 1.0f / fc;
        const float inv_m = 1.0f / (fc - 1.0f);

        float4 MEAN = make_float4(SM.x * inv_c, SM.y * inv_c, SM.z * inv_c, SM.w * inv_c);
        // Unbiased variance, same formula as the reference:
        // var = (sumsq - cnt*mean^2) / (cnt - 1), clamped at 0.
        float4 STD;
        STD.x = sqrtf(fmaxf((SQ.x - fc * MEAN.x * MEAN.x) * inv_m, 0.0f));
        STD.y = sqrtf(fmaxf((SQ.y - fc * MEAN.y * MEAN.y) * inv_m, 0.0f));
        STD.z = sqrtf(fmaxf((SQ.z - fc * MEAN.z * MEAN.z) * inv_m, 0.0f));
        STD.w = sqrtf(fmaxf((SQ.w - fc * MEAN.w * MEAN.w) * inv_m, 0.0f));

        float* base = out + (size_t)g * 4 * D_FEAT + (t << 2);
        *(float4*)(base + 0 * D_FEAT) = MX;
        *(float4*)(base + 1 * D_FEAT) = MN;
        *(float4*)(base + 2 * D_FEAT) = MEAN;
        *(float4*)(base + 3 * D_FEAT) = STD;
    }
}

extern "C" void kernel_launch(void* const* d_in, const int* in_sizes, int n_in,
                              void* d_out, int out_size, void* d_ws, size_t ws_size,
                              hipStream_t stream) {
    const float* x   = (const float*)d_in[0];
    const int*   seg = (const int*)d_in[1];
    float*       out = (float*)d_out;
    int*         offs = (int*)d_ws;        // NUM_SEG+1 ints of scratch
    const int n = in_sizes[0] / D_FEAT;    // 1048576 rows

    seg_bounds_kernel<<<(n + 255) / 256, 256, 0, stream>>>(seg, offs, n);
    seg_pool_kernel<<<NUM_SEG, 128, 0, stream>>>(x, offs, out);
}